// Round 1
// baseline (116.502 us; speedup 1.0000x reference)
//
#include <hip/hip_runtime.h>
#include <math.h>

#define Bb 4
#define Cc 256
#define Hh 128
#define Ww 128
#define HW (Hh * Ww)
#define Kk 9

// Kernel 1: D[b][k][p] = sum_c x[b][c][p] * w[c*9 + k]
// grid = 1024 blocks (4 b * 256 pixel-tiles of 64), block = 256 threads
// = 4 waves; wave i handles channels [i*64, i*64+64).
__global__ __launch_bounds__(256) void proj_kernel(const float* __restrict__ x,
                                                   const float* __restrict__ w,
                                                   float* __restrict__ D) {
    const int tid   = threadIdx.x;
    const int lane  = tid & 63;
    const int chunk = tid >> 6;            // 0..3 (wave-uniform)
    const int bid   = blockIdx.x;          // 0..1023
    const int b     = bid >> 8;
    const int pbase = (bid & 255) << 6;    // 64 pixels per block
    const int p     = pbase + lane;

    // Force wave-uniformity so weight addresses become scalar (s_load) loads.
    const int cu = __builtin_amdgcn_readfirstlane(chunk);
    const float* __restrict__ wp = w + cu * 64 * Kk;
    const float* __restrict__ xp = x + ((size_t)(b * Cc + cu * 64)) * HW + p;

    float acc[Kk];
#pragma unroll
    for (int k = 0; k < Kk; ++k) acc[k] = 0.f;

#pragma unroll 4
    for (int ci = 0; ci < 64; ++ci) {
        float xv = xp[(size_t)ci * HW];
#pragma unroll
        for (int k = 0; k < Kk; ++k) acc[k] += xv * wp[ci * Kk + k];
    }

    // Cross-wave (channel-chunk) reduction in LDS.
    __shared__ float red[4][64][10];       // pad 9 -> 10
#pragma unroll
    for (int k = 0; k < Kk; ++k) red[chunk][lane][k] = acc[k];
    __syncthreads();

    // 576 sums; idx = k*64 + px so D-writes are coalesced per k.
    for (int idx = tid; idx < 64 * Kk; idx += 256) {
        const int k  = idx >> 6;
        const int px = idx & 63;
        float s = red[0][px][k] + red[1][px][k] + red[2][px][k] + red[3][px][k];
        D[((b * Kk + k) * HW) + pbase + px] = s;
    }
}

// Kernel 2: per output pixel, 9 bilinear taps on the 9 projected planes.
__global__ __launch_bounds__(256) void sample_kernel(const float* __restrict__ off,
                                                     const float* __restrict__ D,
                                                     const float* __restrict__ bias,
                                                     float* __restrict__ out) {
    const int g = blockIdx.x * 256 + threadIdx.x;  // 0..65535
    const int b = g >> 14;
    const int p = g & (HW - 1);
    const int h = p >> 7;
    const int w = p & (Ww - 1);

    const float* __restrict__ offb = off + (size_t)b * (2 * Kk) * HW + p;
    const float* __restrict__ Db   = D + (size_t)b * Kk * HW;

    float s = bias[0];

#pragma unroll
    for (int k = 0; k < Kk; ++k) {
        const float dy = offb[(size_t)(2 * k) * HW];
        const float dx = offb[(size_t)(2 * k + 1) * HW];
        const float y  = (float)(h - 1 + (k / 3)) + dy;
        const float xq = (float)(w - 1 + (k % 3)) + dx;

        const float y0f = floorf(y);
        const float x0f = floorf(xq);
        const float wy  = y - y0f;
        const float wx  = xq - x0f;
        const int y0 = (int)y0f;
        const int x0 = (int)x0f;

        const float* __restrict__ Dk = Db + k * HW;

        // 4 corners, zero outside [0,127]^2, clamped index for safe load.
        {
            const int yy = y0, xx = x0;
            const bool valid = (yy >= 0) & (yy < Hh) & (xx >= 0) & (xx < Ww);
            const int yi = min(max(yy, 0), Hh - 1);
            const int xi = min(max(xx, 0), Ww - 1);
            const float v = Dk[yi * Ww + xi];
            s += valid ? (1.f - wy) * (1.f - wx) * v : 0.f;
        }
        {
            const int yy = y0, xx = x0 + 1;
            const bool valid = (yy >= 0) & (yy < Hh) & (xx >= 0) & (xx < Ww);
            const int yi = min(max(yy, 0), Hh - 1);
            const int xi = min(max(xx, 0), Ww - 1);
            const float v = Dk[yi * Ww + xi];
            s += valid ? (1.f - wy) * wx * v : 0.f;
        }
        {
            const int yy = y0 + 1, xx = x0;
            const bool valid = (yy >= 0) & (yy < Hh) & (xx >= 0) & (xx < Ww);
            const int yi = min(max(yy, 0), Hh - 1);
            const int xi = min(max(xx, 0), Ww - 1);
            const float v = Dk[yi * Ww + xi];
            s += valid ? wy * (1.f - wx) * v : 0.f;
        }
        {
            const int yy = y0 + 1, xx = x0 + 1;
            const bool valid = (yy >= 0) & (yy < Hh) & (xx >= 0) & (xx < Ww);
            const int yi = min(max(yy, 0), Hh - 1);
            const int xi = min(max(xx, 0), Ww - 1);
            const float v = Dk[yi * Ww + xi];
            s += valid ? wy * wx * v : 0.f;
        }
    }

    out[g] = 1.f / (1.f + expf(-s));
}

extern "C" void kernel_launch(void* const* d_in, const int* in_sizes, int n_in,
                              void* d_out, int out_size, void* d_ws, size_t ws_size,
                              hipStream_t stream) {
    const float* x    = (const float*)d_in[0];  // [4,256,128,128]
    const float* off  = (const float*)d_in[1];  // [4,18,128,128]
    const float* w    = (const float*)d_in[2];  // [1,256,3,3]
    const float* bias = (const float*)d_in[3];  // [1]
    float* out        = (float*)d_out;          // [4,1,128,128]

    float* D = (float*)d_ws;  // [4][9][16384] f32 = 2.25 MB scratch

    proj_kernel<<<1024, 256, 0, stream>>>(x, w, D);
    sample_kernel<<<256, 256, 0, stream>>>(off, D, bias, out);
}

// Round 2
// 110.696 us; speedup vs baseline: 1.0525x; 1.0525x over previous
//
#include <hip/hip_runtime.h>
#include <math.h>

#define Bb 4
#define Cc 256
#define Hh 128
#define Ww 128
#define HW (Hh * Ww)
#define Kk 9

// ---------------------------------------------------------------------------
// Kernel 1: D[b][k][p] = sum_c x[b][c][p] * w[c*9 + k]
// grid = 256 blocks x 512 threads (8 waves).
// wave wv owns channels [wv*32, wv*32+32); each thread owns 4 consecutive
// pixels loaded as float4 (16B/lane). Block covers 256 pixels.
// Two-phase LDS reduction (8 chunks -> 4 -> final sum) keeps LDS at 36.9 KB.
// ---------------------------------------------------------------------------
__global__ __launch_bounds__(512) void proj_kernel(const float* __restrict__ x,
                                                   const float* __restrict__ w,
                                                   float* __restrict__ D) {
    const int tid   = threadIdx.x;
    const int lane  = tid & 63;
    const int wv    = tid >> 6;            // 0..7
    const int bid   = blockIdx.x;          // 0..255
    const int b     = bid >> 6;            // 64 blocks per batch image
    const int pbase = (bid & 63) << 8;     // 256 pixels per block
    const int p4    = pbase + lane * 4;    // this thread's first pixel

    // wave-uniform channel chunk -> weight addresses become s_loads
    const int cu = __builtin_amdgcn_readfirstlane(wv);
    const float* __restrict__ wp = w + cu * 32 * Kk;
    const float* __restrict__ xp = x + (size_t)(b * Cc + cu * 32) * HW + p4;

    float acc[Kk][4];
#pragma unroll
    for (int k = 0; k < Kk; ++k)
#pragma unroll
        for (int j = 0; j < 4; ++j) acc[k][j] = 0.f;

#pragma unroll 4
    for (int ci = 0; ci < 32; ++ci) {
        const float4 xv = *reinterpret_cast<const float4*>(xp + (size_t)ci * HW);
#pragma unroll
        for (int k = 0; k < Kk; ++k) {
            const float wk = wp[ci * Kk + k];
            acc[k][0] = fmaf(xv.x, wk, acc[k][0]);
            acc[k][1] = fmaf(xv.y, wk, acc[k][1]);
            acc[k][2] = fmaf(xv.z, wk, acc[k][2]);
            acc[k][3] = fmaf(xv.w, wk, acc[k][3]);
        }
    }

    // Two-phase cross-wave reduction: waves 0-3 write, waves 4-7 accumulate.
    __shared__ float red[4][256][Kk];      // 36.9 KB
    if (wv < 4) {
#pragma unroll
        for (int j = 0; j < 4; ++j)
#pragma unroll
            for (int k = 0; k < Kk; ++k) red[wv][lane * 4 + j][k] = acc[k][j];
    }
    __syncthreads();
    if (wv >= 4) {
#pragma unroll
        for (int j = 0; j < 4; ++j)
#pragma unroll
            for (int k = 0; k < Kk; ++k) red[wv - 4][lane * 4 + j][k] += acc[k][j];
    }
    __syncthreads();

    // 2304 outputs (256 px x 9 taps); idx = k*256 + px -> coalesced D writes.
    for (int idx = tid; idx < 256 * Kk; idx += 512) {
        const int k  = idx >> 8;
        const int px = idx & 255;
        const float s = red[0][px][k] + red[1][px][k] + red[2][px][k] + red[3][px][k];
        D[(b * Kk + k) * HW + pbase + px] = s;
    }
}

// ---------------------------------------------------------------------------
// Kernel 2: bilinear-sample the 9 projected planes, reduce, sigmoid.
// grid = 1024 blocks x 192 threads (3 waves). Block covers 64 pixels;
// wave ktrio handles taps {3*ktrio, 3*ktrio+1, 3*ktrio+2}.
// Tap geometry: ky = k/3 = ktrio (wave-uniform), kx = k%3 = j (unrolled).
// ---------------------------------------------------------------------------
__global__ __launch_bounds__(192) void sample_kernel(const float* __restrict__ off,
                                                     const float* __restrict__ D,
                                                     const float* __restrict__ bias,
                                                     float* __restrict__ out) {
    const int tid   = threadIdx.x;         // 0..191
    const int lane  = tid & 63;
    const int ktrio = tid >> 6;            // 0..2
    const int bid   = blockIdx.x;          // 0..1023
    const int b     = bid >> 8;            // 256 blocks per batch image
    const int p     = ((bid & 255) << 6) + lane;
    const int h     = p >> 7;
    const int w_    = p & (Ww - 1);

    const float* __restrict__ offb = off + (size_t)b * (2 * Kk) * HW + p;
    const float* __restrict__ Db   = D + (size_t)b * Kk * HW;

    float s = 0.f;

#pragma unroll
    for (int j = 0; j < 3; ++j) {
        const int k = ktrio * 3 + j;
        const float dy = offb[(size_t)(2 * k) * HW];
        const float dx = offb[(size_t)(2 * k + 1) * HW];
        const float y  = (float)(h - 1 + ktrio) + dy;   // ky == ktrio
        const float xq = (float)(w_ - 1 + j) + dx;      // kx == j

        const float y0f = floorf(y);
        const float x0f = floorf(xq);
        const float wy  = y - y0f;
        const float wx  = xq - x0f;
        const int y0 = (int)y0f;
        const int x0 = (int)x0f;

        const float* __restrict__ Dk = Db + k * HW;

        {
            const int yy = y0, xx = x0;
            const bool valid = (yy >= 0) & (yy < Hh) & (xx >= 0) & (xx < Ww);
            const int yi = min(max(yy, 0), Hh - 1);
            const int xi = min(max(xx, 0), Ww - 1);
            const float v = Dk[yi * Ww + xi];
            s += valid ? (1.f - wy) * (1.f - wx) * v : 0.f;
        }
        {
            const int yy = y0, xx = x0 + 1;
            const bool valid = (yy >= 0) & (yy < Hh) & (xx >= 0) & (xx < Ww);
            const int yi = min(max(yy, 0), Hh - 1);
            const int xi = min(max(xx, 0), Ww - 1);
            const float v = Dk[yi * Ww + xi];
            s += valid ? (1.f - wy) * wx * v : 0.f;
        }
        {
            const int yy = y0 + 1, xx = x0;
            const bool valid = (yy >= 0) & (yy < Hh) & (xx >= 0) & (xx < Ww);
            const int yi = min(max(yy, 0), Hh - 1);
            const int xi = min(max(xx, 0), Ww - 1);
            const float v = Dk[yi * Ww + xi];
            s += valid ? wy * (1.f - wx) * v : 0.f;
        }
        {
            const int yy = y0 + 1, xx = x0 + 1;
            const bool valid = (yy >= 0) & (yy < Hh) & (xx >= 0) & (xx < Ww);
            const int yi = min(max(yy, 0), Hh - 1);
            const int xi = min(max(xx, 0), Ww - 1);
            const float v = Dk[yi * Ww + xi];
            s += valid ? wy * wx * v : 0.f;
        }
    }

    __shared__ float part[3][64];
    part[ktrio][lane] = s;
    __syncthreads();

    if (tid < 64) {
        const float t = part[0][lane] + part[1][lane] + part[2][lane] + bias[0];
        out[(b << 14) + ((bid & 255) << 6) + lane] = 1.f / (1.f + expf(-t));
    }
}

extern "C" void kernel_launch(void* const* d_in, const int* in_sizes, int n_in,
                              void* d_out, int out_size, void* d_ws, size_t ws_size,
                              hipStream_t stream) {
    const float* x    = (const float*)d_in[0];  // [4,256,128,128]
    const float* off  = (const float*)d_in[1];  // [4,18,128,128]
    const float* w    = (const float*)d_in[2];  // [1,256,3,3]
    const float* bias = (const float*)d_in[3];  // [1]
    float* out        = (float*)d_out;          // [4,1,128,128]

    float* D = (float*)d_ws;  // [4][9][16384] f32 = 2.25 MB scratch

    proj_kernel<<<256, 512, 0, stream>>>(x, w, D);
    sample_kernel<<<1024, 192, 0, stream>>>(off, D, bias, out);
}

// Round 3
// 103.724 us; speedup vs baseline: 1.1232x; 1.0672x over previous
//
#include <hip/hip_runtime.h>
#include <math.h>

#define Bb 4
#define Cc 256
#define Hh 128
#define Ww 128
#define HW (Hh * Ww)
#define Kk 9

// ---------------------------------------------------------------------------
// Kernel 1: D[b][k][p] = sum_c x[b][c][p] * w[c*9 + k]
// grid = 512 blocks x 512 threads (8 waves) -> 2 blocks/CU, 16 waves/CU.
// Wave wv owns channels [wv*32, wv*32+32); each thread owns 2 consecutive
// pixels loaded as float2 (8B/lane). Block covers 128 pixels.
// Two-phase LDS reduction (8 chunks -> 4 -> final sum), LDS = 18.4 KB.
// ---------------------------------------------------------------------------
__global__ __launch_bounds__(512) void proj_kernel(const float* __restrict__ x,
                                                   const float* __restrict__ w,
                                                   float* __restrict__ D) {
    const int tid   = threadIdx.x;
    const int lane  = tid & 63;
    const int wv    = tid >> 6;            // 0..7
    const int bid   = blockIdx.x;          // 0..511
    const int b     = bid >> 7;            // 128 blocks per batch image
    const int pbase = (bid & 127) << 7;    // 128 pixels per block
    const int p2    = pbase + lane * 2;    // this thread's first pixel

    // wave-uniform channel chunk -> weight addresses become s_loads
    const int cu = __builtin_amdgcn_readfirstlane(wv);
    const float* __restrict__ wp = w + cu * 32 * Kk;
    const float* __restrict__ xp = x + (size_t)(b * Cc + cu * 32) * HW + p2;

    float acc[Kk][2];
#pragma unroll
    for (int k = 0; k < Kk; ++k) {
        acc[k][0] = 0.f;
        acc[k][1] = 0.f;
    }

#pragma unroll 8
    for (int ci = 0; ci < 32; ++ci) {
        const float2 xv = *reinterpret_cast<const float2*>(xp + (size_t)ci * HW);
#pragma unroll
        for (int k = 0; k < Kk; ++k) {
            const float wk = wp[ci * Kk + k];
            acc[k][0] = fmaf(xv.x, wk, acc[k][0]);
            acc[k][1] = fmaf(xv.y, wk, acc[k][1]);
        }
    }

    // Two-phase cross-wave reduction: waves 0-3 write, waves 4-7 accumulate.
    __shared__ float red[4][128][Kk];      // 18.4 KB
    if (wv < 4) {
#pragma unroll
        for (int j = 0; j < 2; ++j)
#pragma unroll
            for (int k = 0; k < Kk; ++k) red[wv][lane * 2 + j][k] = acc[k][j];
    }
    __syncthreads();
    if (wv >= 4) {
#pragma unroll
        for (int j = 0; j < 2; ++j)
#pragma unroll
            for (int k = 0; k < Kk; ++k) red[wv - 4][lane * 2 + j][k] += acc[k][j];
    }
    __syncthreads();

    // 1152 outputs (128 px x 9 taps); idx = k*128 + px -> coalesced D writes.
    for (int idx = tid; idx < 128 * Kk; idx += 512) {
        const int k  = idx >> 7;
        const int px = idx & 127;
        const float s = red[0][px][k] + red[1][px][k] + red[2][px][k] + red[3][px][k];
        D[(b * Kk + k) * HW + pbase + px] = s;
    }
}

// ---------------------------------------------------------------------------
// Kernel 2: bilinear-sample the 9 projected planes, reduce, sigmoid.
// grid = 1024 blocks x 192 threads (3 waves). Block covers 64 pixels;
// wave ktrio handles taps {3*ktrio, 3*ktrio+1, 3*ktrio+2}.
// Tap geometry: ky = k/3 = ktrio (wave-uniform), kx = k%3 = j (unrolled).
// ---------------------------------------------------------------------------
__global__ __launch_bounds__(192) void sample_kernel(const float* __restrict__ off,
                                                     const float* __restrict__ D,
                                                     const float* __restrict__ bias,
                                                     float* __restrict__ out) {
    const int tid   = threadIdx.x;         // 0..191
    const int lane  = tid & 63;
    const int ktrio = tid >> 6;            // 0..2
    const int bid   = blockIdx.x;          // 0..1023
    const int b     = bid >> 8;            // 256 blocks per batch image
    const int p     = ((bid & 255) << 6) + lane;
    const int h     = p >> 7;
    const int w_    = p & (Ww - 1);

    const float* __restrict__ offb = off + (size_t)b * (2 * Kk) * HW + p;
    const float* __restrict__ Db   = D + (size_t)b * Kk * HW;

    float s = 0.f;

#pragma unroll
    for (int j = 0; j < 3; ++j) {
        const int k = ktrio * 3 + j;
        const float dy = offb[(size_t)(2 * k) * HW];
        const float dx = offb[(size_t)(2 * k + 1) * HW];
        const float y  = (float)(h - 1 + ktrio) + dy;   // ky == ktrio
        const float xq = (float)(w_ - 1 + j) + dx;      // kx == j

        const float y0f = floorf(y);
        const float x0f = floorf(xq);
        const float wy  = y - y0f;
        const float wx  = xq - x0f;
        const int y0 = (int)y0f;
        const int x0 = (int)x0f;

        const float* __restrict__ Dk = Db + k * HW;

        {
            const int yy = y0, xx = x0;
            const bool valid = (yy >= 0) & (yy < Hh) & (xx >= 0) & (xx < Ww);
            const int yi = min(max(yy, 0), Hh - 1);
            const int xi = min(max(xx, 0), Ww - 1);
            const float v = Dk[yi * Ww + xi];
            s += valid ? (1.f - wy) * (1.f - wx) * v : 0.f;
        }
        {
            const int yy = y0, xx = x0 + 1;
            const bool valid = (yy >= 0) & (yy < Hh) & (xx >= 0) & (xx < Ww);
            const int yi = min(max(yy, 0), Hh - 1);
            const int xi = min(max(xx, 0), Ww - 1);
            const float v = Dk[yi * Ww + xi];
            s += valid ? (1.f - wy) * wx * v : 0.f;
        }
        {
            const int yy = y0 + 1, xx = x0;
            const bool valid = (yy >= 0) & (yy < Hh) & (xx >= 0) & (xx < Ww);
            const int yi = min(max(yy, 0), Hh - 1);
            const int xi = min(max(xx, 0), Ww - 1);
            const float v = Dk[yi * Ww + xi];
            s += valid ? wy * (1.f - wx) * v : 0.f;
        }
        {
            const int yy = y0 + 1, xx = x0 + 1;
            const bool valid = (yy >= 0) & (yy < Hh) & (xx >= 0) & (xx < Ww);
            const int yi = min(max(yy, 0), Hh - 1);
            const int xi = min(max(xx, 0), Ww - 1);
            const float v = Dk[yi * Ww + xi];
            s += valid ? wy * wx * v : 0.f;
        }
    }

    __shared__ float part[3][64];
    part[ktrio][lane] = s;
    __syncthreads();

    if (tid < 64) {
        const float t = part[0][lane] + part[1][lane] + part[2][lane] + bias[0];
        out[(b << 14) + ((bid & 255) << 6) + lane] = 1.f / (1.f + expf(-t));
    }
}

extern "C" void kernel_launch(void* const* d_in, const int* in_sizes, int n_in,
                              void* d_out, int out_size, void* d_ws, size_t ws_size,
                              hipStream_t stream) {
    const float* x    = (const float*)d_in[0];  // [4,256,128,128]
    const float* off  = (const float*)d_in[1];  // [4,18,128,128]
    const float* w    = (const float*)d_in[2];  // [1,256,3,3]
    const float* bias = (const float*)d_in[3];  // [1]
    float* out        = (float*)d_out;          // [4,1,128,128]

    float* D = (float*)d_ws;  // [4][9][16384] f32 = 2.25 MB scratch

    proj_kernel<<<512, 512, 0, stream>>>(x, w, D);
    sample_kernel<<<1024, 192, 0, stream>>>(off, D, bias, out);
}